// Round 4
// baseline (458.853 us; speedup 1.0000x reference)
//
#include <hip/hip_runtime.h>

#define NQ 4096
#define NM 8192
#define DK 128
#define DV 512
#define BATCH 2
#define NT (NM / 64)        // 128 m-tiles per batch
#define KTS 8192            // shorts per K tile: 64 rows x 128 dk (tile-linear swizzled)
#define VTILE 16384         // shorts per (b, mtile, dvh) V tile: 256 dv x 64 m

typedef __attribute__((ext_vector_type(8))) short short8;
typedef __attribute__((ext_vector_type(4))) float f32x4;
typedef unsigned short ushort_t;

#define MF(A_, B_, C_) __builtin_amdgcn_mfma_f32_16x16x32_bf16(A_, B_, C_, 0, 0, 0)

static __device__ __forceinline__ unsigned short f2bf(float x) {
    union { float f; unsigned int u; } c; c.f = x;
    unsigned int u = c.u;
    return (unsigned short)((u + 0x7FFFu + ((u >> 16) & 1u)) >> 16);
}
static __device__ __forceinline__ float bf2f(unsigned short h) {
    union { unsigned int u; float f; } c; c.u = ((unsigned int)h) << 16;
    return c.f;
}

// K-tile register fragment load (1KB contiguous per wave per b128)
#define LOADK(AH, AL, itn_) do {                                              \
    const size_t ktb_ = kbase + (size_t)(itn_) * KTS;                         \
    _Pragma("unroll")                                                         \
    for (int ks_ = 0; ks_ < 4; ++ks_) {                                       \
        AH[ks_] = *(const short8*)(kh0 + ktb_ + ks_ * 512);                   \
        AL[ks_] = *(const short8*)(kl0 + ktb_ + ks_ * 512);                   \
    }                                                                         \
} while (0)

// ---------------------------------------------------------------------------
// scan: per-batch compaction of mmask (shfl wave scans). Unchanged.
// ---------------------------------------------------------------------------
__global__ __launch_bounds__(1024) void scan_kernel(
    const int* __restrict__ qmask, const int* __restrict__ mmask,
    int* __restrict__ cidx, int* __restrict__ cpos,
    int* __restrict__ cnts, int* __restrict__ qflags) {
    const int b = blockIdx.x;
    const int t = threadIdx.x;
    const int lane = t & 63;
    const int w = t >> 6;
    __shared__ int wsum[16];
    __shared__ int qsh;

    const int* mp = mmask + b * NM;
    const int base = t * 8;
    int val[8];
#pragma unroll
    for (int i = 0; i < 8; ++i) val[i] = (mp[base + i] != 0);
    int c0 = 0;
#pragma unroll
    for (int i = 0; i < 8; ++i) c0 += val[i];

    int c = c0;
#pragma unroll
    for (int off = 1; off < 64; off <<= 1) {
        int n = __shfl_up(c, off, 64);
        if (lane >= off) c += n;
    }
    if (lane == 63) wsum[w] = c;
    if (t == 0) qsh = 0;
    __syncthreads();
    if (t == 0) {
        int s = 0;
#pragma unroll
        for (int i = 0; i < 16; ++i) { s += wsum[i]; wsum[i] = s; }
    }
    __syncthreads();
    const int wbase = (w == 0) ? 0 : wsum[w - 1];
    int run = wbase + (c - c0);
#pragma unroll
    for (int i = 0; i < 8; ++i) {
        int m = base + i;
        cpos[b * NM + m] = run;
        if (val[i]) { cidx[b * NM + run] = m; ++run; }
    }

    int qa = 0;
    for (int i = t; i < NQ; i += 1024) qa |= (qmask[b * NQ + i] != 0);
    if (qa) atomicOr(&qsh, 1);
    __syncthreads();
    if (t == 0) { cnts[b] = wsum[15]; qflags[b] = qsh; }
}

// ---------------------------------------------------------------------------
// prep Q: transpose [B][DK][NQ] fp32 -> [B][q][DK] bf16 hi/lo (dense rows)
// ---------------------------------------------------------------------------
__global__ __launch_bounds__(256) void prep_q_kernel(
    const float* __restrict__ src, ushort_t* __restrict__ hi,
    ushort_t* __restrict__ lo) {
    const int b = blockIdx.z;
    const int d0 = blockIdx.y * 32;
    const int n0 = blockIdx.x * 32;
    __shared__ float t32[32][33];
    for (int l = threadIdx.x; l < 1024; l += 256) {
        int r = l >> 5, c = l & 31;
        t32[r][c] = src[((size_t)b * DK + d0 + r) * NQ + n0 + c];
    }
    __syncthreads();
    for (int l = threadIdx.x; l < 1024; l += 256) {
        int r = l >> 5, c = l & 31;
        float f = t32[c][r];
        unsigned short h = f2bf(f);
        unsigned short lw = f2bf(f - bf2f(h));
        size_t off = ((size_t)b * NQ + n0 + r) * DK + d0 + c;
        hi[off] = h;
        lo[off] = lw;
    }
}

// ---------------------------------------------------------------------------
// prep K: transpose + compacting gather -> tile-linear swizzled image.
// Per 64-row tile (16 KB): [w:4][ks:4][quad:4][col:16] x 8 shorts, so a wave's
// b128 fragment read (w,ks fixed; lane = quad*16+col) is one contiguous 1 KB.
// ---------------------------------------------------------------------------
__global__ __launch_bounds__(256) void prep_k_kernel(
    const float* __restrict__ src, const int* __restrict__ mmask,
    const int* __restrict__ cpos,
    ushort_t* __restrict__ hi, ushort_t* __restrict__ lo) {
    const int b = blockIdx.z;
    const int d0 = blockIdx.y * 32;
    const int n0 = blockIdx.x * 32;
    __shared__ float t32[32][33];
    for (int l = threadIdx.x; l < 1024; l += 256) {
        int r = l >> 5, c = l & 31;
        t32[r][c] = src[((size_t)b * DK + d0 + r) * NM + n0 + c];
    }
    __syncthreads();
    for (int l = threadIdx.x; l < 1024; l += 256) {
        int r = l >> 5, c = l & 31;
        int m = n0 + r;
        if (mmask[b * NM + m] != 0) {
            int pos = cpos[b * NM + m];
            float f = t32[c][r];
            unsigned short h = f2bf(f);
            unsigned short lw = f2bf(f - bf2f(h));
            int d = d0 + c;
            size_t off = ((size_t)(b * NT + (pos >> 6))) * KTS
                       + ((pos >> 4) & 3) * 2048 + (d >> 5) * 512
                       + ((d >> 3) & 3) * 128 + (pos & 15) * 8 + (d & 7);
            hi[off] = h;
            lo[off] = lw;
        }
    }
}

// ---------------------------------------------------------------------------
// prep V: gather + convert -> tile-linear swizzled V image.
// Per (b, mtile, dvh) 32 KB tile: [w:4][vt:4][ks2:2][quad:4][col:16] x 8 shorts
// so each pv b128 V-fragment read is one contiguous 1 KB per wave.
// ---------------------------------------------------------------------------
__global__ __launch_bounds__(256) void prep_v_kernel(
    const float* __restrict__ src, const int* __restrict__ cidx,
    const int* __restrict__ cnts, ushort_t* __restrict__ dst) {
    const int mt = blockIdx.x;
    const int dvb = blockIdx.y;
    const int b = blockIdx.z;
    const int cnt = cnts[b];
    const int tr = threadIdx.x >> 2;
    const int part = threadIdx.x & 3;
    const int dv = dvb * 64 + tr;
    const int dvh = dv >> 8, rr = dv & 255;
    const int wq = rr >> 6, vt = (rr >> 4) & 3, cl = rr & 15;
    const int ks2 = part >> 1, quad0 = (part & 1) * 2;

    const float* row = src + ((size_t)b * DV + dv) * NM;
    const int* cx = cidx + b * NM + mt * 64 + part * 16;
    ushort_t o[16];
#pragma unroll
    for (int i = 0; i < 16; ++i) {
        int m = mt * 64 + part * 16 + i;
        int idx = (m < cnt) ? cx[i] : 0;
        o[i] = (m < cnt) ? f2bf(row[idx]) : (ushort_t)0;
    }
    ushort_t* dp = dst + (((size_t)(b * NT + mt)) * 2 + dvh) * VTILE
                 + wq * 4096 + vt * 1024 + ks2 * 512 + quad0 * 128 + cl * 8;
    *(short8*)dp = *(short8*)&o[0];
    *(short8*)(dp + 128) = *(short8*)&o[8];
}

// ---------------------------------------------------------------------------
// stats-lite: hi*hi-only max per (q-tile, m-quarter). No exp, no l, no Q-lo.
// (gmax only needs to be within +-60 of the true max: the softmax shift
//  rescales P, l, O identically; finalize adds a +8 margin covering the
//  dropped lo-product residual, sigma ~= 0.7.)  8 MFMAs + fmax per tile.
// grid 1024 = 128 qt x 4 parts x 2 b, 256 thr.
// ---------------------------------------------------------------------------
__global__ __launch_bounds__(256, 4) void stats_kernel(
    const ushort_t* __restrict__ Qhi, const ushort_t* __restrict__ Khi,
    const int* __restrict__ cnts, float* __restrict__ mpart) {
    const int t = threadIdx.x;
    const int lane = t & 63;
    const int w = t >> 6;
    const int quad = lane >> 4;
    const int col = lane & 15;
    const int bid = blockIdx.x;
    const int part = bid & 3;
    const int b = (bid >> 2) & 1;
    const int qb = (bid >> 3) * 32;

    const int cnt = cnts[b];
    const int nit = (cnt + 63) >> 6;
    const int it0 = (nit * part) >> 2;
    const int it1 = (nit * (part + 1)) >> 2;

    __shared__ float red_m[4][32];

    short8 qfh[2][4];
    {
        const ushort_t* qhp = Qhi + ((size_t)b * NQ + qb) * DK;
#pragma unroll
        for (int qt = 0; qt < 2; ++qt)
#pragma unroll
            for (int ks = 0; ks < 4; ++ks)
                qfh[qt][ks] = *(const short8*)(qhp + (size_t)(qt * 16 + col) * DK + ks * 32 + quad * 8);
    }

    const f32x4 zero4 = {0.f, 0.f, 0.f, 0.f};
    float mloc[2] = {-3.0e38f, -3.0e38f};
    const ushort_t* kh0 = Khi + w * 2048 + lane * 8;
    const size_t kbase = (size_t)(b * NT) * KTS;

#define LOADKH(A_, itn_) do {                                                 \
    const size_t ktb_ = kbase + (size_t)(itn_) * KTS;                         \
    _Pragma("unroll")                                                         \
    for (int ks_ = 0; ks_ < 4; ++ks_)                                         \
        A_[ks_] = *(const short8*)(kh0 + ktb_ + ks_ * 512);                   \
} while (0)

#define STPH(CK, NK, it_, itn_) do {                                          \
    LOADKH(NK, itn_);                                                         \
    f32x4 aS0 = zero4, aS1 = zero4;                                           \
    _Pragma("unroll")                                                         \
    for (int ks = 0; ks < 4; ++ks) {                                          \
        aS0 = MF(CK[ks], qfh[0][ks], aS0);                                    \
        aS1 = MF(CK[ks], qfh[1][ks], aS1);                                    \
    }                                                                         \
    const int mrow_ = (it_) * 64 + w * 16 + quad * 4;                         \
    _Pragma("unroll")                                                         \
    for (int r = 0; r < 4; ++r) {                                             \
        if (mrow_ + r < cnt) {                                                \
            mloc[0] = fmaxf(mloc[0], aS0[r] * 40.0f);                         \
            mloc[1] = fmaxf(mloc[1], aS1[r] * 40.0f);                         \
        }                                                                     \
    }                                                                         \
} while (0)

    short8 kA[4], kB[4];
    int it = it0;
    if (it < it1) {
        LOADKH(kA, it);
        int itn;
        while (true) {
            itn = (it + 1 < it1) ? it + 1 : it;
            STPH(kA, kB, it, itn);
            if (++it >= it1) break;
            itn = (it + 1 < it1) ? it + 1 : it;
            STPH(kB, kA, it, itn);
            if (++it >= it1) break;
        }
    }
#undef STPH
#undef LOADKH

#pragma unroll
    for (int qt = 0; qt < 2; ++qt) {
        float m = mloc[qt];
        m = fmaxf(m, __shfl_xor(m, 16, 64));
        m = fmaxf(m, __shfl_xor(m, 32, 64));
        if (lane < 16) red_m[w][qt * 16 + col] = m;
    }
    __syncthreads();
    if (t < 32) {
        float M = -3.0e38f;
#pragma unroll
        for (int ww = 0; ww < 4; ++ww) M = fmaxf(M, red_m[ww][t]);
        mpart[((size_t)(b * 4 + part)) * NQ + qb + t] = M;
    }
}

// ---------------------------------------------------------------------------
// finalize: merge 4 max parts + margin for the dropped lo-products.
// ---------------------------------------------------------------------------
__global__ __launch_bounds__(256) void finalize_kernel(
    const float* __restrict__ mpart, float* __restrict__ gmaxb) {
    const int i = blockIdx.x * 256 + threadIdx.x;   // < BATCH*NQ
    const int b = i >> 12;
    const int q = i & (NQ - 1);
    float M = -3.0e38f;
#pragma unroll
    for (int c = 0; c < 4; ++c)
        M = fmaxf(M, mpart[((size_t)(b * 4 + c)) * NQ + q]);
    gmaxb[i] = M + 8.0f;
}

// ---------------------------------------------------------------------------
// pv: software-pipelined by one m-tile. Phase it: {ds_read P[it-1] (top,
// hidden under QK), load V[it] (reg dbuf), QK[it], issue K[it+1], P[it]->LDS,
// PV[it-1], lgkmcnt(0)+s_barrier (NO vmcnt drain -> loads stay in flight)}.
// Exact per-chunk l via all-ones A-fragment MFMA (w==0, dvh==0 blocks only).
// grid 1024 = 128 qt x (2 b x 2 dvh) x 2 chunks, 256 thr.
// ---------------------------------------------------------------------------
__global__ __launch_bounds__(256, 2) void pv_kernel(
    const ushort_t* __restrict__ Qhi, const ushort_t* __restrict__ Qlo,
    const ushort_t* __restrict__ Khi, const ushort_t* __restrict__ Klo,
    const ushort_t* __restrict__ Vimg, const int* __restrict__ cnts,
    const float* __restrict__ gmaxb, float* __restrict__ out0,
    float* __restrict__ out1, float* __restrict__ lsum) {
    const int t = threadIdx.x;
    const int lane = t & 63;
    const int w = t >> 6;
    const int quad = lane >> 4;
    const int col = lane & 15;
    const int bid = blockIdx.x;
    const int chunk = bid & 1;          // low bits: (chunk,b,dvh) -> XCD-resident
    const int cmb = (bid >> 1) & 3;
    const int b = cmb >> 1;
    const int dvh = cmb & 1;
    const int qb = (bid >> 3) * 32;

    const int cnt = cnts[b];
    const int nit = (cnt + 63) >> 6;
    const int nh = (nit + 1) >> 1;
    const int it0 = chunk ? nh : 0;
    const int it1 = chunk ? nit : nh;

    __shared__ __align__(16) ushort_t P_s[2][32][68];

    const float gm0 = gmaxb[(size_t)b * NQ + qb + col];
    const float gm1 = gmaxb[(size_t)b * NQ + qb + 16 + col];

    short8 qfh[2][4], qfl[2][4];
    {
        const ushort_t* qhp = Qhi + ((size_t)b * NQ + qb) * DK;
        const ushort_t* qlp = Qlo + ((size_t)b * NQ + qb) * DK;
#pragma unroll
        for (int qt = 0; qt < 2; ++qt)
#pragma unroll
            for (int ks = 0; ks < 4; ++ks) {
                size_t off = (size_t)(qt * 16 + col) * DK + ks * 32 + quad * 8;
                qfh[qt][ks] = *(const short8*)(qhp + off);
                qfl[qt][ks] = *(const short8*)(qlp + off);
            }
    }

    const ushort_t* kh0 = Khi + w * 2048 + lane * 8;
    const ushort_t* kl0 = Klo + w * 2048 + lane * 8;
    const size_t kbase = (size_t)(b * NT) * KTS;
    const ushort_t* vl0 = Vimg + ((size_t)(b * NT) * 2 + dvh) * VTILE
                        + w * 4096 + lane * 8;

    const f32x4 zero4 = {0.f, 0.f, 0.f, 0.f};
    const short8 vones = {(short)0x3F80, (short)0x3F80, (short)0x3F80,
                          (short)0x3F80, (short)0x3F80, (short)0x3F80,
                          (short)0x3F80, (short)0x3F80};
    const bool doL = (dvh == 0) && (w == 0);
    f32x4 accO[4][2];
#pragma unroll
    for (int vt = 0; vt < 4; ++vt)
#pragma unroll
        for (int qt = 0; qt < 2; ++qt) accO[vt][qt] = zero4;
    f32x4 accL0 = zero4, accL1 = zero4;

#define LOADV(VB_, it_) do {                                                  \
    const ushort_t* vp_ = vl0 + (size_t)(it_) * (2 * VTILE);                  \
    _Pragma("unroll")                                                         \
    for (int vt_ = 0; vt_ < 4; ++vt_) {                                       \
        VB_[vt_][0] = *(const short8*)(vp_ + vt_ * 1024);                     \
        VB_[vt_][1] = *(const short8*)(vp_ + vt_ * 1024 + 512);               \
    }                                                                         \
} while (0)

#define QKBLK() do {                                                          \
    _Pragma("unroll")                                                         \
    for (int ks = 0; ks < 4; ++ks) {                                          \
        aS0 = MF(kh[ks], qfh[0][ks], aS0); aS1 = MF(kh[ks], qfh[1][ks], aS1); \
        aS0 = MF(kh[ks], qfl[0][ks], aS0); aS1 = MF(kh[ks], qfl[1][ks], aS1); \
        aS0 = MF(kl[ks], qfh[0][ks], aS0); aS1 = MF(kl[ks], qfh[1][ks], aS1); \
    }                                                                         \
} while (0)

#define PSTORE(PW_, it_) do {                                                 \
    const int mrow_ = (it_) * 64 + w * 16 + quad * 4;                         \
    float p_[4]; ushort4 pk_;                                                 \
    _Pragma("unroll")                                                         \
    for (int r = 0; r < 4; ++r)                                               \
        p_[r] = (mrow_ + r < cnt) ? __expf(aS0[r] * 40.0f - gm0) : 0.0f;      \
    pk_.x = f2bf(p_[0]); pk_.y = f2bf(p_[1]);                                 \
    pk_.z = f2bf(p_[2]); pk_.w = f2bf(p_[3]);                                 \
    *(ushort4*)&P_s[PW_][col][w * 16 + quad * 4] = pk_;                       \
    _Pragma("unroll")                                                         \
    for (int r = 0; r < 4; ++r)                                               \
        p_[r] = (mrow_ + r < cnt) ? __expf(aS1[r] * 40.0f - gm1) : 0.0f;      \
    pk_.x = f2bf(p_[0]); pk_.y = f2bf(p_[1]);                                 \
    pk_.z = f2bf(p_[2]); pk_.w = f2bf(p_[3]);                                 \
    *(ushort4*)&P_s[PW_][16 + col][w * 16 + quad * 4] = pk_;                  \
} while (0)

#define PVBLK(VB_) do {                                                       \
    _Pragma("unroll")                                                         \
    for (int vt = 0; vt < 4; ++vt) {                                          \
        accO[vt][0] = MF(VB_[vt][0], pr0a, accO[vt][0]);                      \
        accO[vt][1] = MF(VB_[vt][0], pr1a, accO[vt][1]);                      \
        accO[vt][0] = MF(VB_[vt][1], pr0b, accO[vt][0]);                      \
        accO[vt][1] = MF(VB_[vt][1], pr1b, accO[vt][1]);                      \
    }                                                                         \
    if (doL) {                                                                \
        accL0 = MF(vones, pr0a, accL0); accL0 = MF(vones, pr0b, accL0);       \
        accL1 = MF(vones, pr1a, accL1); accL1 = MF(vones, pr1b, accL1);       \
    }                                                                         \
} while (0)

#define PHASE(VNEW, VOLD, PW, PR, it_) do {                                   \
    short8 pr0a = *(const short8*)&P_s[PR][col][quad * 8];                    \
    short8 pr0b = *(const short8*)&P_s[PR][col][32 + quad * 8];               \
    short8 pr1a = *(const short8*)&P_s[PR][16 + col][quad * 8];               \
    short8 pr1b = *(const short8*)&P_s[PR][16 + col][32 + quad * 8];          \
    LOADV(VNEW, it_);                                                         \
    f32x4 aS0 = zero4, aS1 = zero4;                                           \
    QKBLK();                                                                  \
    { int itn_ = ((it_) + 1 < it1) ? (it_) + 1 : (it_);                       \
      LOADK(kh, kl, itn_); }                                                  \
    PSTORE(PW, it_);                                                          \
    PVBLK(VOLD);                                                              \
    asm volatile("s_waitcnt lgkmcnt(0)" ::: "memory");                        \
    __builtin_amdgcn_s_barrier();                                             \
    __builtin_amdgcn_sched_barrier(0);                                        \
} while (0)

    short8 kh[4], kl[4];
    short8 vA[4][2], vB[4][2];
    int it = it0;
    if (it < it1) {
        LOADK(kh, kl, it);
        LOADV(vA, it);
        {   // prologue phase: QK[it0] only, P -> LDS[0]
            f32x4 aS0 = zero4, aS1 = zero4;
            QKBLK();
            { int itn_ = (it + 1 < it1) ? it + 1 : it; LOADK(kh, kl, itn_); }
            PSTORE(0, it);
        }
        asm volatile("s_waitcnt lgkmcnt(0)" ::: "memory");
        __builtin_amdgcn_s_barrier();
        __builtin_amdgcn_sched_barrier(0);
        ++it;
        while (it < it1) {
            PHASE(vB, vA, 1, 0, it);
            if (++it >= it1) break;
            PHASE(vA, vB, 0, 1, it);
            if (++it >= it1) break;
        }
        // epilogue: PV[it1-1]; its P is in LDS[lastp], its V in (lastp? vB:vA)
        const int lastp = (it1 - 1 - it0) & 1;
        if (lastp) {
            short8 pr0a = *(const short8*)&P_s[1][col][quad * 8];
            short8 pr0b = *(const short8*)&P_s[1][col][32 + quad * 8];
            short8 pr1a = *(const short8*)&P_s[1][16 + col][quad * 8];
            short8 pr1b = *(const short8*)&P_s[1][16 + col][32 + quad * 8];
            PVBLK(vB);
        } else {
            short8 pr0a = *(const short8*)&P_s[0][col][quad * 8];
            short8 pr0b = *(const short8*)&P_s[0][col][32 + quad * 8];
            short8 pr1a = *(const short8*)&P_s[0][16 + col][quad * 8];
            short8 pr1b = *(const short8*)&P_s[0][16 + col][32 + quad * 8];
            PVBLK(vA);
        }
    }
#undef PHASE
#undef PVBLK
#undef PSTORE
#undef QKBLK
#undef LOADV

    // ---- epilogue: raw partial sums (normalization+gating in combine) ----
    float* pbase = chunk ? out1 : out0;
#pragma unroll
    for (int qt = 0; qt < 2; ++qt) {
        const int q = qb + qt * 16 + col;
#pragma unroll
        for (int vt = 0; vt < 4; ++vt)
#pragma unroll
            for (int r = 0; r < 4; ++r) {
                int dv = dvh * 256 + w * 64 + vt * 16 + quad * 4 + r;
                pbase[((size_t)b * DV + dv) * NQ + q] = accO[vt][qt][r];
            }
    }
    // exact per-chunk softmax denominator (all rows of accL identical)
    if (doL && lane < 32) {
        float lv = (lane < 16) ? accL0[0] : accL1[0];
        lsum[((size_t)(b * 2 + chunk)) * NQ + qb + lane] = lv;
    }
}

// ---------------------------------------------------------------------------
// combine: out = gated (p0 + p1) / (l0 + l1)   (p0 aliases out; elementwise)
// ---------------------------------------------------------------------------
__global__ __launch_bounds__(256) void combine_kernel(
    const float* p0, const float* __restrict__ p1,
    const float* __restrict__ lsum, const int* __restrict__ cnts,
    const int* __restrict__ qflags, const int* __restrict__ qmask,
    float* out) {
    const size_t i = ((size_t)blockIdx.x * 256 + threadIdx.x) * 4;
    const int b = (int)(i >> 21);          // DV*NQ = 2^21
    const int q = (int)(i & (NQ - 1));
    f32x4 a = *(const f32x4*)(p0 + i);
    f32x4 c = *(const f32x4*)(p1 + i);
    f32x4 l0 = *(const f32x4*)(lsum + (size_t)(b * 2) * NQ + q);
    f32x4 l1 = *(const f32x4*)(lsum + (size_t)(b * 2 + 1) * NQ + q);
    const int4 qm = *(const int4*)(qmask + b * NQ + q);
    const bool bv = (qflags[b] != 0) && (cnts[b] > 0);
    f32x4 r;
    float lv;
    lv = l0[0] + l1[0]; r[0] = (bv && qm.x && lv > 0.f) ? (a[0] + c[0]) / lv : 0.f;
    lv = l0[1] + l1[1]; r[1] = (bv && qm.y && lv > 0.f) ? (a[1] + c[1]) / lv : 0.f;
    lv = l0[2] + l1[2]; r[2] = (bv && qm.z && lv > 0.f) ? (a[2] + c[2]) / lv : 0.f;
    lv = l0[3] + l1[3]; r[3] = (bv && qm.w && lv > 0.f) ? (a[3] + c[3]) / lv : 0.f;
    *(f32x4*)(out + i) = r;
}

// ---------------------------------------------------------------------------
extern "C" void kernel_launch(void* const* d_in, const int* in_sizes, int n_in,
                              void* d_out, int out_size, void* d_ws, size_t ws_size,
                              hipStream_t stream) {
    const float* qkey  = (const float*)d_in[0];
    // d_in[1] (qval) unused by the reference
    const int*   qmask = (const int*)d_in[2];
    const float* mkey  = (const float*)d_in[3];
    const float* mval  = (const float*)d_in[4];
    const int*   mmask = (const int*)d_in[5];
    float* out = (float*)d_out;

    char* ws = (char*)d_ws;
    size_t off = 0;
    const size_t QS  = (size_t)BATCH * NQ * DK * 2;          // 2 MB each
    const size_t KS2 = (size_t)BATCH * NM * DK * 2;          // 4 MB each (swizzled)
    const size_t VS  = (size_t)BATCH * NT * 2 * VTILE * 2;   // 16 MB
    const size_t OS  = (size_t)BATCH * DV * NQ * 4;          // 16.8 MB
    ushort_t* Qhi = (ushort_t*)(ws + off); off += QS;
    ushort_t* Qlo = (ushort_t*)(ws + off); off += QS;
    ushort_t* Khi = (ushort_t*)(ws + off); off += KS2;
    ushort_t* Klo = (ushort_t*)(ws + off); off += KS2;
    ushort_t* Vc  = (ushort_t*)(ws + off); off += VS;
    float* part1  = (float*)(ws + off); off += OS;           // chunk-1 partial
    float* mpart  = (float*)(ws + off); off += (size_t)BATCH * 4 * NQ * 4;
    float* gmaxb  = (float*)(ws + off); off += (size_t)BATCH * NQ * 4;
    float* lsum   = (float*)(ws + off); off += (size_t)BATCH * 2 * NQ * 4;
    int* cidx     = (int*)(ws + off); off += (size_t)BATCH * NM * 4;
    int* cpos     = (int*)(ws + off); off += (size_t)BATCH * NM * 4;
    int* cnts     = (int*)(ws + off); off += 64;
    int* qflags   = (int*)(ws + off); off += 64;

    scan_kernel<<<BATCH, 1024, 0, stream>>>(qmask, mmask, cidx, cpos, cnts, qflags);

    dim3 gq(NQ / 32, DK / 32, BATCH);
    prep_q_kernel<<<gq, 256, 0, stream>>>(qkey, Qhi, Qlo);
    dim3 gk(NM / 32, DK / 32, BATCH);
    prep_k_kernel<<<gk, 256, 0, stream>>>(mkey, mmask, cpos, Khi, Klo);
    dim3 gv(NM / 64, DV / 64, BATCH);
    prep_v_kernel<<<gv, 256, 0, stream>>>(mval, cidx, cnts, Vc);

    stats_kernel<<<(NQ / 32) * 8, 256, 0, stream>>>(Qhi, Khi, cnts, mpart);
    finalize_kernel<<<(BATCH * NQ) / 256, 256, 0, stream>>>(mpart, gmaxb);

    pv_kernel<<<(NQ / 32) * 8, 256, 0, stream>>>(
        Qhi, Qlo, Khi, Klo, Vc, cnts, gmaxb, out, part1, lsum);

    combine_kernel<<<(int)((size_t)BATCH * DV * NQ / 1024), 256, 0, stream>>>(
        out, part1, lsum, cnts, qflags, qmask, out);
}

// Round 5
// 282.331 us; speedup vs baseline: 1.6252x; 1.6252x over previous
//
#include <hip/hip_runtime.h>

#define NQ 4096
#define NM 8192
#define DK 128
#define DV 512
#define BATCH 2
#define NT (NM / 64)        // 128 m-tiles per batch
#define KTS 8192            // shorts per K tile: 64 rows x 128 dk (tile-linear swizzled)
#define VTILE 16384         // shorts per (b, mtile, dvh) V tile: 256 dv x 64 m

typedef __attribute__((ext_vector_type(8))) short short8;
typedef __attribute__((ext_vector_type(4))) float f32x4;
typedef unsigned short ushort_t;

#define MF(A_, B_, C_) __builtin_amdgcn_mfma_f32_16x16x32_bf16(A_, B_, C_, 0, 0, 0)

static __device__ __forceinline__ unsigned short f2bf(float x) {
    union { float f; unsigned int u; } c; c.f = x;
    unsigned int u = c.u;
    return (unsigned short)((u + 0x7FFFu + ((u >> 16) & 1u)) >> 16);
}
static __device__ __forceinline__ float bf2f(unsigned short h) {
    union { unsigned int u; float f; } c; c.u = ((unsigned int)h) << 16;
    return c.f;
}

// K-tile register fragment load (1KB contiguous per wave per b128)
#define LOADK(AH, AL, itn_) do {                                              \
    const size_t ktb_ = kbase + (size_t)(itn_) * KTS;                         \
    _Pragma("unroll")                                                         \
    for (int ks_ = 0; ks_ < 4; ++ks_) {                                       \
        AH[ks_] = *(const short8*)(kh0 + ktb_ + ks_ * 512);                   \
        AL[ks_] = *(const short8*)(kl0 + ktb_ + ks_ * 512);                   \
    }                                                                         \
} while (0)

// ---------------------------------------------------------------------------
// scan: per-batch compaction of mmask (shfl wave scans). Unchanged.
// ---------------------------------------------------------------------------
__global__ __launch_bounds__(1024) void scan_kernel(
    const int* __restrict__ qmask, const int* __restrict__ mmask,
    int* __restrict__ cidx, int* __restrict__ cpos,
    int* __restrict__ cnts, int* __restrict__ qflags) {
    const int b = blockIdx.x;
    const int t = threadIdx.x;
    const int lane = t & 63;
    const int w = t >> 6;
    __shared__ int wsum[16];
    __shared__ int qsh;

    const int* mp = mmask + b * NM;
    const int base = t * 8;
    int val[8];
#pragma unroll
    for (int i = 0; i < 8; ++i) val[i] = (mp[base + i] != 0);
    int c0 = 0;
#pragma unroll
    for (int i = 0; i < 8; ++i) c0 += val[i];

    int c = c0;
#pragma unroll
    for (int off = 1; off < 64; off <<= 1) {
        int n = __shfl_up(c, off, 64);
        if (lane >= off) c += n;
    }
    if (lane == 63) wsum[w] = c;
    if (t == 0) qsh = 0;
    __syncthreads();
    if (t == 0) {
        int s = 0;
#pragma unroll
        for (int i = 0; i < 16; ++i) { s += wsum[i]; wsum[i] = s; }
    }
    __syncthreads();
    const int wbase = (w == 0) ? 0 : wsum[w - 1];
    int run = wbase + (c - c0);
#pragma unroll
    for (int i = 0; i < 8; ++i) {
        int m = base + i;
        cpos[b * NM + m] = run;
        if (val[i]) { cidx[b * NM + run] = m; ++run; }
    }

    int qa = 0;
    for (int i = t; i < NQ; i += 1024) qa |= (qmask[b * NQ + i] != 0);
    if (qa) atomicOr(&qsh, 1);
    __syncthreads();
    if (t == 0) { cnts[b] = wsum[15]; qflags[b] = qsh; }
}

// ---------------------------------------------------------------------------
// prep Q: transpose [B][DK][NQ] fp32 -> [B][q][DK] bf16 hi/lo (dense rows)
// ---------------------------------------------------------------------------
__global__ __launch_bounds__(256) void prep_q_kernel(
    const float* __restrict__ src, ushort_t* __restrict__ hi,
    ushort_t* __restrict__ lo) {
    const int b = blockIdx.z;
    const int d0 = blockIdx.y * 32;
    const int n0 = blockIdx.x * 32;
    __shared__ float t32[32][33];
    for (int l = threadIdx.x; l < 1024; l += 256) {
        int r = l >> 5, c = l & 31;
        t32[r][c] = src[((size_t)b * DK + d0 + r) * NQ + n0 + c];
    }
    __syncthreads();
    for (int l = threadIdx.x; l < 1024; l += 256) {
        int r = l >> 5, c = l & 31;
        float f = t32[c][r];
        unsigned short h = f2bf(f);
        unsigned short lw = f2bf(f - bf2f(h));
        size_t off = ((size_t)b * NQ + n0 + r) * DK + d0 + c;
        hi[off] = h;
        lo[off] = lw;
    }
}

// ---------------------------------------------------------------------------
// prep K: transpose + compacting gather -> tile-linear swizzled image.
// Per 64-row tile (16 KB): [w:4][ks:4][quad:4][col:16] x 8 shorts, so a wave's
// b128 fragment read (w,ks fixed; lane = quad*16+col) is one contiguous 1 KB.
// ---------------------------------------------------------------------------
__global__ __launch_bounds__(256) void prep_k_kernel(
    const float* __restrict__ src, const int* __restrict__ mmask,
    const int* __restrict__ cpos,
    ushort_t* __restrict__ hi, ushort_t* __restrict__ lo) {
    const int b = blockIdx.z;
    const int d0 = blockIdx.y * 32;
    const int n0 = blockIdx.x * 32;
    __shared__ float t32[32][33];
    for (int l = threadIdx.x; l < 1024; l += 256) {
        int r = l >> 5, c = l & 31;
        t32[r][c] = src[((size_t)b * DK + d0 + r) * NM + n0 + c];
    }
    __syncthreads();
    for (int l = threadIdx.x; l < 1024; l += 256) {
        int r = l >> 5, c = l & 31;
        int m = n0 + r;
        if (mmask[b * NM + m] != 0) {
            int pos = cpos[b * NM + m];
            float f = t32[c][r];
            unsigned short h = f2bf(f);
            unsigned short lw = f2bf(f - bf2f(h));
            int d = d0 + c;
            size_t off = ((size_t)(b * NT + (pos >> 6))) * KTS
                       + ((pos >> 4) & 3) * 2048 + (d >> 5) * 512
                       + ((d >> 3) & 3) * 128 + (pos & 15) * 8 + (d & 7);
            hi[off] = h;
            lo[off] = lw;
        }
    }
}

// ---------------------------------------------------------------------------
// prep V: gather + convert -> tile-linear swizzled V image.
// Per (b, mtile, dvh) 32 KB tile: [w:4][vt:4][ks2:2][quad:4][col:16] x 8 shorts
// so each pv b128 V-fragment read is one contiguous 1 KB per wave.
// ---------------------------------------------------------------------------
__global__ __launch_bounds__(256) void prep_v_kernel(
    const float* __restrict__ src, const int* __restrict__ cidx,
    const int* __restrict__ cnts, ushort_t* __restrict__ dst) {
    const int mt = blockIdx.x;
    const int dvb = blockIdx.y;
    const int b = blockIdx.z;
    const int cnt = cnts[b];
    const int tr = threadIdx.x >> 2;
    const int part = threadIdx.x & 3;
    const int dv = dvb * 64 + tr;
    const int dvh = dv >> 8, rr = dv & 255;
    const int wq = rr >> 6, vt = (rr >> 4) & 3, cl = rr & 15;
    const int ks2 = part >> 1, quad0 = (part & 1) * 2;

    const float* row = src + ((size_t)b * DV + dv) * NM;
    const int* cx = cidx + b * NM + mt * 64 + part * 16;
    ushort_t o[16];
#pragma unroll
    for (int i = 0; i < 16; ++i) {
        int m = mt * 64 + part * 16 + i;
        int idx = (m < cnt) ? cx[i] : 0;
        o[i] = (m < cnt) ? f2bf(row[idx]) : (ushort_t)0;
    }
    ushort_t* dp = dst + (((size_t)(b * NT + mt)) * 2 + dvh) * VTILE
                 + wq * 4096 + vt * 1024 + ks2 * 512 + quad0 * 128 + cl * 8;
    *(short8*)dp = *(short8*)&o[0];
    *(short8*)(dp + 128) = *(short8*)&o[8];
}

// ---------------------------------------------------------------------------
// stats-lite: hi*hi-only max per (q-tile, m-quarter). No exp, no l, no Q-lo.
// finalize adds +8 margin covering the dropped lo-product residual.
// grid 1024 = 128 qt x 4 parts x 2 b, 256 thr.
// ---------------------------------------------------------------------------
__global__ __launch_bounds__(256, 4) void stats_kernel(
    const ushort_t* __restrict__ Qhi, const ushort_t* __restrict__ Khi,
    const int* __restrict__ cnts, float* __restrict__ mpart) {
    const int t = threadIdx.x;
    const int lane = t & 63;
    const int w = t >> 6;
    const int quad = lane >> 4;
    const int col = lane & 15;
    const int bid = blockIdx.x;
    const int part = bid & 3;
    const int b = (bid >> 2) & 1;
    const int qb = (bid >> 3) * 32;

    const int cnt = cnts[b];
    const int nit = (cnt + 63) >> 6;
    const int it0 = (nit * part) >> 2;
    const int it1 = (nit * (part + 1)) >> 2;

    __shared__ float red_m[4][32];

    short8 qfh[2][4];
    {
        const ushort_t* qhp = Qhi + ((size_t)b * NQ + qb) * DK;
#pragma unroll
        for (int qt = 0; qt < 2; ++qt)
#pragma unroll
            for (int ks = 0; ks < 4; ++ks)
                qfh[qt][ks] = *(const short8*)(qhp + (size_t)(qt * 16 + col) * DK + ks * 32 + quad * 8);
    }

    const f32x4 zero4 = {0.f, 0.f, 0.f, 0.f};
    float mloc[2] = {-3.0e38f, -3.0e38f};
    const ushort_t* kh0 = Khi + w * 2048 + lane * 8;
    const size_t kbase = (size_t)(b * NT) * KTS;

#define LOADKH(A_, itn_) do {                                                 \
    const size_t ktb_ = kbase + (size_t)(itn_) * KTS;                         \
    _Pragma("unroll")                                                         \
    for (int ks_ = 0; ks_ < 4; ++ks_)                                         \
        A_[ks_] = *(const short8*)(kh0 + ktb_ + ks_ * 512);                   \
} while (0)

#define STPH(CK, NK, it_, itn_) do {                                          \
    LOADKH(NK, itn_);                                                         \
    f32x4 aS0 = zero4, aS1 = zero4;                                           \
    _Pragma("unroll")                                                         \
    for (int ks = 0; ks < 4; ++ks) {                                          \
        aS0 = MF(CK[ks], qfh[0][ks], aS0);                                    \
        aS1 = MF(CK[ks], qfh[1][ks], aS1);                                    \
    }                                                                         \
    const int mrow_ = (it_) * 64 + w * 16 + quad * 4;                         \
    _Pragma("unroll")                                                         \
    for (int r = 0; r < 4; ++r) {                                             \
        if (mrow_ + r < cnt) {                                                \
            mloc[0] = fmaxf(mloc[0], aS0[r] * 40.0f);                         \
            mloc[1] = fmaxf(mloc[1], aS1[r] * 40.0f);                         \
        }                                                                     \
    }                                                                         \
} while (0)

    short8 kA[4], kB[4];
    int it = it0;
    if (it < it1) {
        LOADKH(kA, it);
        int itn;
        while (true) {
            itn = (it + 1 < it1) ? it + 1 : it;
            STPH(kA, kB, it, itn);
            if (++it >= it1) break;
            itn = (it + 1 < it1) ? it + 1 : it;
            STPH(kB, kA, it, itn);
            if (++it >= it1) break;
        }
    }
#undef STPH
#undef LOADKH

#pragma unroll
    for (int qt = 0; qt < 2; ++qt) {
        float m = mloc[qt];
        m = fmaxf(m, __shfl_xor(m, 16, 64));
        m = fmaxf(m, __shfl_xor(m, 32, 64));
        if (lane < 16) red_m[w][qt * 16 + col] = m;
    }
    __syncthreads();
    if (t < 32) {
        float M = -3.0e38f;
#pragma unroll
        for (int ww = 0; ww < 4; ++ww) M = fmaxf(M, red_m[ww][t]);
        mpart[((size_t)(b * 4 + part)) * NQ + qb + t] = M;
    }
}

// ---------------------------------------------------------------------------
// finalize: merge 4 max parts + margin for the dropped lo-products.
// ---------------------------------------------------------------------------
__global__ __launch_bounds__(256) void finalize_kernel(
    const float* __restrict__ mpart, float* __restrict__ gmaxb) {
    const int i = blockIdx.x * 256 + threadIdx.x;   // < BATCH*NQ
    const int b = i >> 12;
    const int q = i & (NQ - 1);
    float M = -3.0e38f;
#pragma unroll
    for (int c = 0; c < 4; ++c)
        M = fmaxf(M, mpart[((size_t)(b * 4 + c)) * NQ + q]);
    gmaxb[i] = M + 8.0f;
}

// ---------------------------------------------------------------------------
// pv: round-2 structure (no spills) + issue-order fix. Per phase:
//   issue V[it] (8 loads) -> QK (vmcnt wait drains only K-cur, V in flight)
//   -> issue K[it+1] (reg dbuf) -> P->LDS -> lgkmcnt(0)+s_barrier (NO vmcnt
//   drain) -> PV (vmcnt wait drains only V, K-next stays in flight).
// Exact per-chunk l via all-ones A-fragment MFMA (w==0, dvh==0 waves).
// grid 1024 = 128 qt x (2 b x 2 dvh) x 2 chunks, 256 thr.
// ---------------------------------------------------------------------------
__global__ __launch_bounds__(256, 2) void pv_kernel(
    const ushort_t* __restrict__ Qhi, const ushort_t* __restrict__ Qlo,
    const ushort_t* __restrict__ Khi, const ushort_t* __restrict__ Klo,
    const ushort_t* __restrict__ Vimg, const int* __restrict__ cnts,
    const float* __restrict__ gmaxb, float* __restrict__ out0,
    float* __restrict__ out1, float* __restrict__ lsum) {
    const int t = threadIdx.x;
    const int lane = t & 63;
    const int w = t >> 6;
    const int quad = lane >> 4;
    const int col = lane & 15;
    const int bid = blockIdx.x;
    const int chunk = bid & 1;          // low bits: (chunk,b,dvh) -> XCD-resident
    const int cmb = (bid >> 1) & 3;
    const int b = cmb >> 1;
    const int dvh = cmb & 1;
    const int qb = (bid >> 3) * 32;

    const int cnt = cnts[b];
    const int nit = (cnt + 63) >> 6;
    const int nh = (nit + 1) >> 1;
    const int it0 = chunk ? nh : 0;
    const int it1 = chunk ? nit : nh;

    __shared__ __align__(16) ushort_t P_s[2][32][68];

    const float gm0 = gmaxb[(size_t)b * NQ + qb + col];
    const float gm1 = gmaxb[(size_t)b * NQ + qb + 16 + col];

    short8 qfh[2][4], qfl[2][4];
    {
        const ushort_t* qhp = Qhi + ((size_t)b * NQ + qb) * DK;
        const ushort_t* qlp = Qlo + ((size_t)b * NQ + qb) * DK;
#pragma unroll
        for (int qt = 0; qt < 2; ++qt)
#pragma unroll
            for (int ks = 0; ks < 4; ++ks) {
                size_t off = (size_t)(qt * 16 + col) * DK + ks * 32 + quad * 8;
                qfh[qt][ks] = *(const short8*)(qhp + off);
                qfl[qt][ks] = *(const short8*)(qlp + off);
            }
    }

    const ushort_t* kh0 = Khi + w * 2048 + lane * 8;
    const ushort_t* kl0 = Klo + w * 2048 + lane * 8;
    const size_t kbase = (size_t)(b * NT) * KTS;
    const ushort_t* vl0 = Vimg + ((size_t)(b * NT) * 2 + dvh) * VTILE
                        + w * 4096 + lane * 8;

    const f32x4 zero4 = {0.f, 0.f, 0.f, 0.f};
    const short8 vones = {(short)0x3F80, (short)0x3F80, (short)0x3F80,
                          (short)0x3F80, (short)0x3F80, (short)0x3F80,
                          (short)0x3F80, (short)0x3F80};
    const bool doL = (dvh == 0) && (w == 0);
    f32x4 accO[4][2];
#pragma unroll
    for (int vt = 0; vt < 4; ++vt)
#pragma unroll
        for (int qt = 0; qt < 2; ++qt) accO[vt][qt] = zero4;
    f32x4 accL0 = zero4, accL1 = zero4;

// One phase (V scoped inside -> no cross-phase V liveness, no spills)
#define PV_PHASE(CKH, CKL, NKH, NKL, PB, it_, itn_) do {                      \
    const ushort_t* vp_ = vl0 + (size_t)(it_) * (2 * VTILE);                  \
    short8 vf_[4][2];                                                         \
    _Pragma("unroll")                                                         \
    for (int vt = 0; vt < 4; ++vt) {                                          \
        vf_[vt][0] = *(const short8*)(vp_ + vt * 1024);                       \
        vf_[vt][1] = *(const short8*)(vp_ + vt * 1024 + 512);                 \
    }                                                                         \
    f32x4 aS0 = zero4, aS1 = zero4;                                           \
    _Pragma("unroll")                                                         \
    for (int ks = 0; ks < 4; ++ks) {                                          \
        aS0 = MF(CKH[ks], qfh[0][ks], aS0); aS1 = MF(CKH[ks], qfh[1][ks], aS1); \
        aS0 = MF(CKH[ks], qfl[0][ks], aS0); aS1 = MF(CKH[ks], qfl[1][ks], aS1); \
        aS0 = MF(CKL[ks], qfh[0][ks], aS0); aS1 = MF(CKL[ks], qfh[1][ks], aS1); \
    }                                                                         \
    LOADK(NKH, NKL, itn_);                                                    \
    const int mrow_ = (it_) * 64 + w * 16 + quad * 4;                         \
    {                                                                         \
        float p_[4]; ushort4 pk_;                                             \
        _Pragma("unroll")                                                     \
        for (int r = 0; r < 4; ++r)                                           \
            p_[r] = (mrow_ + r < cnt) ? __expf(aS0[r] * 40.0f - gm0) : 0.0f;  \
        pk_.x = f2bf(p_[0]); pk_.y = f2bf(p_[1]);                             \
        pk_.z = f2bf(p_[2]); pk_.w = f2bf(p_[3]);                             \
        *(ushort4*)&P_s[PB][col][w * 16 + quad * 4] = pk_;                    \
        _Pragma("unroll")                                                     \
        for (int r = 0; r < 4; ++r)                                           \
            p_[r] = (mrow_ + r < cnt) ? __expf(aS1[r] * 40.0f - gm1) : 0.0f;  \
        pk_.x = f2bf(p_[0]); pk_.y = f2bf(p_[1]);                             \
        pk_.z = f2bf(p_[2]); pk_.w = f2bf(p_[3]);                             \
        *(ushort4*)&P_s[PB][16 + col][w * 16 + quad * 4] = pk_;               \
    }                                                                         \
    asm volatile("s_waitcnt lgkmcnt(0)" ::: "memory");                        \
    __builtin_amdgcn_s_barrier();                                             \
    __builtin_amdgcn_sched_barrier(0);                                        \
    _Pragma("unroll")                                                         \
    for (int k2 = 0; k2 < 2; ++k2) {                                          \
        short8 pb0_ = *(const short8*)&P_s[PB][col][k2 * 32 + quad * 8];      \
        short8 pb1_ = *(const short8*)&P_s[PB][16 + col][k2 * 32 + quad * 8]; \
        _Pragma("unroll")                                                     \
        for (int vt = 0; vt < 4; ++vt) {                                      \
            accO[vt][0] = MF(vf_[vt][k2], pb0_, accO[vt][0]);                 \
            accO[vt][1] = MF(vf_[vt][k2], pb1_, accO[vt][1]);                 \
        }                                                                     \
        if (doL) {                                                            \
            accL0 = MF(vones, pb0_, accL0);                                   \
            accL1 = MF(vones, pb1_, accL1);                                   \
        }                                                                     \
    }                                                                         \
} while (0)

    short8 kAh[4], kAl[4], kBh[4], kBl[4];
    int it = it0;
    if (it < it1) {
        LOADK(kAh, kAl, it);
        int itn;
        while (true) {
            itn = (it + 1 < it1) ? it + 1 : it;
            PV_PHASE(kAh, kAl, kBh, kBl, 0, it, itn);
            if (++it >= it1) break;
            itn = (it + 1 < it1) ? it + 1 : it;
            PV_PHASE(kBh, kBl, kAh, kAl, 1, it, itn);
            if (++it >= it1) break;
        }
    }
#undef PV_PHASE

    // ---- epilogue: raw partial sums (normalization+gating in combine) ----
    float* pbase = chunk ? out1 : out0;
#pragma unroll
    for (int qt = 0; qt < 2; ++qt) {
        const int q = qb + qt * 16 + col;
#pragma unroll
        for (int vt = 0; vt < 4; ++vt)
#pragma unroll
            for (int r = 0; r < 4; ++r) {
                int dv = dvh * 256 + w * 64 + vt * 16 + quad * 4 + r;
                pbase[((size_t)b * DV + dv) * NQ + q] = accO[vt][qt][r];
            }
    }
    // exact per-chunk softmax denominator (all rows of accL identical)
    if (doL && lane < 32) {
        float lv = (lane < 16) ? accL0[0] : accL1[0];
        lsum[((size_t)(b * 2 + chunk)) * NQ + qb + lane] = lv;
    }
}

// ---------------------------------------------------------------------------
// combine: out = gated (p0 + p1) / (l0 + l1)   (p0 aliases out; elementwise)
// ---------------------------------------------------------------------------
__global__ __launch_bounds__(256) void combine_kernel(
    const float* p0, const float* __restrict__ p1,
    const float* __restrict__ lsum, const int* __restrict__ cnts,
    const int* __restrict__ qflags, const int* __restrict__ qmask,
    float* out) {
    const size_t i = ((size_t)blockIdx.x * 256 + threadIdx.x) * 4;
    const int b = (int)(i >> 21);          // DV*NQ = 2^21
    const int q = (int)(i & (NQ - 1));
    f32x4 a = *(const f32x4*)(p0 + i);
    f32x4 c = *(const f32x4*)(p1 + i);
    f32x4 l0 = *(const f32x4*)(lsum + (size_t)(b * 2) * NQ + q);
    f32x4 l1 = *(const f32x4*)(lsum + (size_t)(b * 2 + 1) * NQ + q);
    const int4 qm = *(const int4*)(qmask + b * NQ + q);
    const bool bv = (qflags[b] != 0) && (cnts[b] > 0);
    f32x4 r;
    float lv;
    lv = l0[0] + l1[0]; r[0] = (bv && qm.x && lv > 0.f) ? (a[0] + c[0]) / lv : 0.f;
    lv = l0[1] + l1[1]; r[1] = (bv && qm.y && lv > 0.f) ? (a[1] + c[1]) / lv : 0.f;
    lv = l0[2] + l1[2]; r[2] = (bv && qm.z && lv > 0.f) ? (a[2] + c[2]) / lv : 0.f;
    lv = l0[3] + l1[3]; r[3] = (bv && qm.w && lv > 0.f) ? (a[3] + c[3]) / lv : 0.f;
    *(f32x4*)(out + i) = r;
}

// ---------------------------------------------------------------------------
extern "C" void kernel_launch(void* const* d_in, const int* in_sizes, int n_in,
                              void* d_out, int out_size, void* d_ws, size_t ws_size,
                              hipStream_t stream) {
    const float* qkey  = (const float*)d_in[0];
    // d_in[1] (qval) unused by the reference
    const int*   qmask = (const int*)d_in[2];
    const float* mkey  = (const float*)d_in[3];
    const float* mval  = (const float*)d_in[4];
    const int*   mmask = (const int*)d_in[5];
    float* out = (float*)d_out;

    char* ws = (char*)d_ws;
    size_t off = 0;
    const size_t QS  = (size_t)BATCH * NQ * DK * 2;          // 2 MB each
    const size_t KS2 = (size_t)BATCH * NM * DK * 2;          // 4 MB each (swizzled)
    const size_t VS  = (size_t)BATCH * NT * 2 * VTILE * 2;   // 16 MB
    const size_t OS  = (size_t)BATCH * DV * NQ * 4;          // 16.8 MB
    ushort_t* Qhi = (ushort_t*)(ws + off); off += QS;
    ushort_t* Qlo = (ushort_t*)(ws + off); off += QS;
    ushort_t* Khi = (ushort_t*)(ws + off); off += KS2;
    ushort_t* Klo = (ushort_t*)(ws + off); off += KS2;
    ushort_t* Vc  = (ushort_t*)(ws + off); off += VS;
    float* part1  = (float*)(ws + off); off += OS;           // chunk-1 partial
    float* mpart  = (float*)(ws + off); off += (size_t)BATCH * 4 * NQ * 4;
    float* gmaxb  = (float*)(ws + off); off += (size_t)BATCH * NQ * 4;
    float* lsum   = (float*)(ws + off); off += (size_t)BATCH * 2 * NQ * 4;
    int* cidx     = (int*)(ws + off); off += (size_t)BATCH * NM * 4;
    int* cpos     = (int*)(ws + off); off += (size_t)BATCH * NM * 4;
    int* cnts     = (int*)(ws + off); off += 64;
    int* qflags   = (int*)(ws + off); off += 64;

    scan_kernel<<<BATCH, 1024, 0, stream>>>(qmask, mmask, cidx, cpos, cnts, qflags);

    dim3 gq(NQ / 32, DK / 32, BATCH);
    prep_q_kernel<<<gq, 256, 0, stream>>>(qkey, Qhi, Qlo);
    dim3 gk(NM / 32, DK / 32, BATCH);
    prep_k_kernel<<<gk, 256, 0, stream>>>(mkey, mmask, cpos, Khi, Klo);
    dim3 gv(NM / 64, DV / 64, BATCH);
    prep_v_kernel<<<gv, 256, 0, stream>>>(mval, cidx, cnts, Vc);

    stats_kernel<<<(NQ / 32) * 8, 256, 0, stream>>>(Qhi, Khi, cnts, mpart);
    finalize_kernel<<<(BATCH * NQ) / 256, 256, 0, stream>>>(mpart, gmaxb);

    pv_kernel<<<(NQ / 32) * 8, 256, 0, stream>>>(
        Qhi, Qlo, Khi, Klo, Vc, cnts, gmaxb, out, part1, lsum);

    combine_kernel<<<(int)((size_t)BATCH * DV * NQ / 1024), 256, 0, stream>>>(
        out, part1, lsum, cnts, qflags, qmask, out);
}

// Round 6
// 234.805 us; speedup vs baseline: 1.9542x; 1.2024x over previous
//
#include <hip/hip_runtime.h>

#define NQ 4096
#define NM 8192
#define DK 128
#define DV 512
#define BATCH 2
#define NT (NM / 64)        // 128 m-tiles per batch
#define KTS 8192            // shorts per K tile: 64 rows x 128 dk (tile-linear swizzled)
#define VTILE 16384         // shorts per (b, mtile, dvh) V tile: 256 dv x 64 m

typedef __attribute__((ext_vector_type(8))) short short8;
typedef __attribute__((ext_vector_type(4))) float f32x4;
typedef unsigned short ushort_t;

#define MF(A_, B_, C_) __builtin_amdgcn_mfma_f32_16x16x32_bf16(A_, B_, C_, 0, 0, 0)

static __device__ __forceinline__ unsigned short f2bf(float x) {
    union { float f; unsigned int u; } c; c.f = x;
    unsigned int u = c.u;
    return (unsigned short)((u + 0x7FFFu + ((u >> 16) & 1u)) >> 16);
}
static __device__ __forceinline__ float bf2f(unsigned short h) {
    union { unsigned int u; float f; } c; c.u = ((unsigned int)h) << 16;
    return c.f;
}

// swizzled V-image address for (compacted pos, dv) within batch image
static __device__ __forceinline__ size_t vaddr(int b, int pos, int dv) {
    const int mt = pos >> 6, m64 = pos & 63;
    const int dvh = dv >> 8, rr = dv & 255;
    return (((size_t)(b * NT + mt) * 2 + dvh) * VTILE)
         + (rr >> 6) * 4096 + ((rr >> 4) & 3) * 1024
         + (m64 >> 5) * 512
         + ((((m64 >> 4) & 1) * 2 + ((m64 >> 3) & 1)) * 128)
         + (rr & 15) * 8 + (m64 & 7);
}

// K-tile register fragment load (1KB contiguous per wave per b128)
#define LOADK(AH, AL, itn_) do {                                              \
    const size_t ktb_ = kbase + (size_t)(itn_) * KTS;                         \
    _Pragma("unroll")                                                         \
    for (int ks_ = 0; ks_ < 4; ++ks_) {                                       \
        AH[ks_] = *(const short8*)(kh0 + ktb_ + ks_ * 512);                   \
        AL[ks_] = *(const short8*)(kl0 + ktb_ + ks_ * 512);                   \
    }                                                                         \
} while (0)

// ---------------------------------------------------------------------------
// scan: per-batch compaction of mmask (shfl wave scans). Unchanged.
// ---------------------------------------------------------------------------
__global__ __launch_bounds__(1024) void scan_kernel(
    const int* __restrict__ qmask, const int* __restrict__ mmask,
    int* __restrict__ cidx, int* __restrict__ cpos,
    int* __restrict__ cnts, int* __restrict__ qflags) {
    const int b = blockIdx.x;
    const int t = threadIdx.x;
    const int lane = t & 63;
    const int w = t >> 6;
    __shared__ int wsum[16];
    __shared__ int qsh;

    const int* mp = mmask + b * NM;
    const int base = t * 8;
    int val[8];
#pragma unroll
    for (int i = 0; i < 8; ++i) val[i] = (mp[base + i] != 0);
    int c0 = 0;
#pragma unroll
    for (int i = 0; i < 8; ++i) c0 += val[i];

    int c = c0;
#pragma unroll
    for (int off = 1; off < 64; off <<= 1) {
        int n = __shfl_up(c, off, 64);
        if (lane >= off) c += n;
    }
    if (lane == 63) wsum[w] = c;
    if (t == 0) qsh = 0;
    __syncthreads();
    if (t == 0) {
        int s = 0;
#pragma unroll
        for (int i = 0; i < 16; ++i) { s += wsum[i]; wsum[i] = s; }
    }
    __syncthreads();
    const int wbase = (w == 0) ? 0 : wsum[w - 1];
    int run = wbase + (c - c0);
#pragma unroll
    for (int i = 0; i < 8; ++i) {
        int m = base + i;
        cpos[b * NM + m] = run;
        if (val[i]) { cidx[b * NM + run] = m; ++run; }
    }

    int qa = 0;
    for (int i = t; i < NQ; i += 1024) qa |= (qmask[b * NQ + i] != 0);
    if (qa) atomicOr(&qsh, 1);
    __syncthreads();
    if (t == 0) { cnts[b] = wsum[15]; qflags[b] = qsh; }
}

// ---------------------------------------------------------------------------
// prep Q: transpose [B][DK][NQ] fp32 -> [B][q][DK] bf16 hi/lo (dense rows)
// ---------------------------------------------------------------------------
__global__ __launch_bounds__(256) void prep_q_kernel(
    const float* __restrict__ src, ushort_t* __restrict__ hi,
    ushort_t* __restrict__ lo) {
    const int b = blockIdx.z;
    const int d0 = blockIdx.y * 32;
    const int n0 = blockIdx.x * 32;
    __shared__ float t32[32][33];
    for (int l = threadIdx.x; l < 1024; l += 256) {
        int r = l >> 5, c = l & 31;
        t32[r][c] = src[((size_t)b * DK + d0 + r) * NQ + n0 + c];
    }
    __syncthreads();
    for (int l = threadIdx.x; l < 1024; l += 256) {
        int r = l >> 5, c = l & 31;
        float f = t32[c][r];
        unsigned short h = f2bf(f);
        unsigned short lw = f2bf(f - bf2f(h));
        size_t off = ((size_t)b * NQ + n0 + r) * DK + d0 + c;
        hi[off] = h;
        lo[off] = lw;
    }
}

// ---------------------------------------------------------------------------
// prep K: transpose + compacting gather -> tile-linear swizzled image.
// Per 64-row tile (16 KB): [w:4][ks:4][quad:4][col:16] x 8 shorts, so a wave's
// b128 fragment read (w,ks fixed; lane = quad*16+col) is one contiguous 1 KB.
// ---------------------------------------------------------------------------
__global__ __launch_bounds__(256) void prep_k_kernel(
    const float* __restrict__ src, const int* __restrict__ mmask,
    const int* __restrict__ cpos,
    ushort_t* __restrict__ hi, ushort_t* __restrict__ lo) {
    const int b = blockIdx.z;
    const int d0 = blockIdx.y * 32;
    const int n0 = blockIdx.x * 32;
    __shared__ float t32[32][33];
    for (int l = threadIdx.x; l < 1024; l += 256) {
        int r = l >> 5, c = l & 31;
        t32[r][c] = src[((size_t)b * DK + d0 + r) * NM + n0 + c];
    }
    __syncthreads();
    for (int l = threadIdx.x; l < 1024; l += 256) {
        int r = l >> 5, c = l & 31;
        int m = n0 + r;
        if (mmask[b * NM + m] != 0) {
            int pos = cpos[b * NM + m];
            float f = t32[c][r];
            unsigned short h = f2bf(f);
            unsigned short lw = f2bf(f - bf2f(h));
            int d = d0 + c;
            size_t off = ((size_t)(b * NT + (pos >> 6))) * KTS
                       + ((pos >> 4) & 3) * 2048 + (d >> 5) * 512
                       + ((d >> 3) & 3) * 128 + (pos & 15) * 8 + (d & 7);
            hi[off] = h;
            lo[off] = lw;
        }
    }
}

// ---------------------------------------------------------------------------
// prep V (dense-read compaction): read mval coalesced (float4 along m),
// predicated-write bf16 to the swizzled compacted V image (monotone pos ->
// near-dense writes). blockIdx.y==8 branch zero-fills only the tail tile.
// grid (DV/8, 9, B), 256 thr.
// ---------------------------------------------------------------------------
__global__ __launch_bounds__(256) void prep_v_kernel(
    const float* __restrict__ src, const int* __restrict__ mmask,
    const int* __restrict__ cpos, const int* __restrict__ cnts,
    ushort_t* __restrict__ dst) {
    const int b = blockIdx.z;
    const int dv0 = blockIdx.x * 8;
    if (blockIdx.y == 8) {   // tail-tile zero fill: pos in [cnt, nit*64)
        const int cnt = cnts[b];
        const int pend = ((cnt + 63) >> 6) * 64;
        const int dv = dv0 + (threadIdx.x >> 5);
        for (int p = cnt + (threadIdx.x & 31); p < pend; p += 32)
            dst[vaddr(b, p, dv)] = 0;
        return;
    }
    const int m = blockIdx.y * 1024 + threadIdx.x * 4;
    const int4 mm = *(const int4*)(mmask + b * NM + m);
    const int4 cp = *(const int4*)(cpos + b * NM + m);
#pragma unroll
    for (int i = 0; i < 8; ++i) {
        const int dv = dv0 + i;
        const float4 v = *(const float4*)(src + ((size_t)b * DV + dv) * NM + m);
        if (mm.x) dst[vaddr(b, cp.x, dv)] = f2bf(v.x);
        if (mm.y) dst[vaddr(b, cp.y, dv)] = f2bf(v.y);
        if (mm.z) dst[vaddr(b, cp.z, dv)] = f2bf(v.z);
        if (mm.w) dst[vaddr(b, cp.w, dv)] = f2bf(v.w);
    }
}

// ---------------------------------------------------------------------------
// stats-lite: hi*hi-only max per (q-tile, m-quarter). No exp, no l, no Q-lo.
// pv merges the 4 parts and adds the +8 margin itself.
// grid 1024 = 128 qt x 4 parts x 2 b, 256 thr.
// ---------------------------------------------------------------------------
__global__ __launch_bounds__(256, 4) void stats_kernel(
    const ushort_t* __restrict__ Qhi, const ushort_t* __restrict__ Khi,
    const int* __restrict__ cnts, float* __restrict__ mpart) {
    const int t = threadIdx.x;
    const int lane = t & 63;
    const int w = t >> 6;
    const int quad = lane >> 4;
    const int col = lane & 15;
    const int bid = blockIdx.x;
    const int part = bid & 3;
    const int b = (bid >> 2) & 1;
    const int qb = (bid >> 3) * 32;

    const int cnt = cnts[b];
    const int nit = (cnt + 63) >> 6;
    const int it0 = (nit * part) >> 2;
    const int it1 = (nit * (part + 1)) >> 2;

    __shared__ float red_m[4][32];

    short8 qfh[2][4];
    {
        const ushort_t* qhp = Qhi + ((size_t)b * NQ + qb) * DK;
#pragma unroll
        for (int qt = 0; qt < 2; ++qt)
#pragma unroll
            for (int ks = 0; ks < 4; ++ks)
                qfh[qt][ks] = *(const short8*)(qhp + (size_t)(qt * 16 + col) * DK + ks * 32 + quad * 8);
    }

    const f32x4 zero4 = {0.f, 0.f, 0.f, 0.f};
    float mloc[2] = {-3.0e38f, -3.0e38f};
    const ushort_t* kh0 = Khi + w * 2048 + lane * 8;
    const size_t kbase = (size_t)(b * NT) * KTS;

#define LOADKH(A_, itn_) do {                                                 \
    const size_t ktb_ = kbase + (size_t)(itn_) * KTS;                         \
    _Pragma("unroll")                                                         \
    for (int ks_ = 0; ks_ < 4; ++ks_)                                         \
        A_[ks_] = *(const short8*)(kh0 + ktb_ + ks_ * 512);                   \
} while (0)

#define STPH(CK, NK, it_, itn_) do {                                          \
    LOADKH(NK, itn_);                                                         \
    f32x4 aS0 = zero4, aS1 = zero4;                                           \
    _Pragma("unroll")                                                         \
    for (int ks = 0; ks < 4; ++ks) {                                          \
        aS0 = MF(CK[ks], qfh[0][ks], aS0);                                    \
        aS1 = MF(CK[ks], qfh[1][ks], aS1);                                    \
    }                                                                         \
    const int mrow_ = (it_) * 64 + w * 16 + quad * 4;                         \
    _Pragma("unroll")                                                         \
    for (int r = 0; r < 4; ++r) {                                             \
        if (mrow_ + r < cnt) {                                                \
            mloc[0] = fmaxf(mloc[0], aS0[r] * 40.0f);                         \
            mloc[1] = fmaxf(mloc[1], aS1[r] * 40.0f);                         \
        }                                                                     \
    }                                                                         \
} while (0)

    short8 kA[4], kB[4];
    int it = it0;
    if (it < it1) {
        LOADKH(kA, it);
        int itn;
        while (true) {
            itn = (it + 1 < it1) ? it + 1 : it;
            STPH(kA, kB, it, itn);
            if (++it >= it1) break;
            itn = (it + 1 < it1) ? it + 1 : it;
            STPH(kB, kA, it, itn);
            if (++it >= it1) break;
        }
    }
#undef STPH
#undef LOADKH

#pragma unroll
    for (int qt = 0; qt < 2; ++qt) {
        float m = mloc[qt];
        m = fmaxf(m, __shfl_xor(m, 16, 64));
        m = fmaxf(m, __shfl_xor(m, 32, 64));
        if (lane < 16) red_m[w][qt * 16 + col] = m;
    }
    __syncthreads();
    if (t < 32) {
        float M = -3.0e38f;
#pragma unroll
        for (int ww = 0; ww < 4; ++ww) M = fmaxf(M, red_m[ww][t]);
        mpart[((size_t)(b * 4 + part)) * NQ + qb + t] = M;
    }
}

// ---------------------------------------------------------------------------
// pv: round-5 phase structure, de-chunked (full m-range in-block). The exact
// denominator accL completes in-block -> final normalized gated fp32 output
// written directly (no part1, no combine). gmax merge (+8 margin) inlined.
// grid 512 = 128 qt x (2 b x 2 dvh), 256 thr.
// ---------------------------------------------------------------------------
__global__ __launch_bounds__(256, 2) void pv_kernel(
    const ushort_t* __restrict__ Qhi, const ushort_t* __restrict__ Qlo,
    const ushort_t* __restrict__ Khi, const ushort_t* __restrict__ Klo,
    const ushort_t* __restrict__ Vimg, const int* __restrict__ cnts,
    const int* __restrict__ qflags, const int* __restrict__ qmask,
    const float* __restrict__ mpart, float* __restrict__ out) {
    const int t = threadIdx.x;
    const int lane = t & 63;
    const int w = t >> 6;
    const int quad = lane >> 4;
    const int col = lane & 15;
    const int bid = blockIdx.x;
    const int cmb = bid & 3;            // low bits (b,dvh) -> XCD-resident
    const int b = cmb >> 1;
    const int dvh = cmb & 1;
    const int qb = (bid >> 2) * 32;

    const int cnt = cnts[b];
    const int it1 = (cnt + 63) >> 6;

    __shared__ __align__(16) ushort_t P_s[2][32][68];
    __shared__ float l_s[32];

    // inline finalize: merge 4 stats parts + margin for dropped lo-products
    float gm0, gm1;
    {
        float M0 = -3.0e38f, M1 = -3.0e38f;
#pragma unroll
        for (int c = 0; c < 4; ++c) {
            M0 = fmaxf(M0, mpart[((size_t)(b * 4 + c)) * NQ + qb + col]);
            M1 = fmaxf(M1, mpart[((size_t)(b * 4 + c)) * NQ + qb + 16 + col]);
        }
        gm0 = M0 + 8.0f;
        gm1 = M1 + 8.0f;
    }

    short8 qfh[2][4], qfl[2][4];
    {
        const ushort_t* qhp = Qhi + ((size_t)b * NQ + qb) * DK;
        const ushort_t* qlp = Qlo + ((size_t)b * NQ + qb) * DK;
#pragma unroll
        for (int qt = 0; qt < 2; ++qt)
#pragma unroll
            for (int ks = 0; ks < 4; ++ks) {
                size_t off = (size_t)(qt * 16 + col) * DK + ks * 32 + quad * 8;
                qfh[qt][ks] = *(const short8*)(qhp + off);
                qfl[qt][ks] = *(const short8*)(qlp + off);
            }
    }

    const ushort_t* kh0 = Khi + w * 2048 + lane * 8;
    const ushort_t* kl0 = Klo + w * 2048 + lane * 8;
    const size_t kbase = (size_t)(b * NT) * KTS;
    const ushort_t* vl0 = Vimg + ((size_t)(b * NT) * 2 + dvh) * VTILE
                        + w * 4096 + lane * 8;

    const f32x4 zero4 = {0.f, 0.f, 0.f, 0.f};
    const short8 vones = {(short)0x3F80, (short)0x3F80, (short)0x3F80,
                          (short)0x3F80, (short)0x3F80, (short)0x3F80,
                          (short)0x3F80, (short)0x3F80};
    const bool doL = (w == 0);
    f32x4 accO[4][2];
#pragma unroll
    for (int vt = 0; vt < 4; ++vt)
#pragma unroll
        for (int qt = 0; qt < 2; ++qt) accO[vt][qt] = zero4;
    f32x4 accL0 = zero4, accL1 = zero4;

// One phase (V scoped inside -> no cross-phase V liveness, no spills)
#define PV_PHASE(CKH, CKL, NKH, NKL, PB, it_, itn_) do {                      \
    const ushort_t* vp_ = vl0 + (size_t)(it_) * (2 * VTILE);                  \
    short8 vf_[4][2];                                                         \
    _Pragma("unroll")                                                         \
    for (int vt = 0; vt < 4; ++vt) {                                          \
        vf_[vt][0] = *(const short8*)(vp_ + vt * 1024);                       \
        vf_[vt][1] = *(const short8*)(vp_ + vt * 1024 + 512);                 \
    }                                                                         \
    f32x4 aS0 = zero4, aS1 = zero4;                                           \
    _Pragma("unroll")                                                         \
    for (int ks = 0; ks < 4; ++ks) {                                          \
        aS0 = MF(CKH[ks], qfh[0][ks], aS0); aS1 = MF(CKH[ks], qfh[1][ks], aS1); \
        aS0 = MF(CKH[ks], qfl[0][ks], aS0); aS1 = MF(CKH[ks], qfl[1][ks], aS1); \
        aS0 = MF(CKL[ks], qfh[0][ks], aS0); aS1 = MF(CKL[ks], qfh[1][ks], aS1); \
    }                                                                         \
    LOADK(NKH, NKL, itn_);                                                    \
    const int mrow_ = (it_) * 64 + w * 16 + quad * 4;                         \
    {                                                                         \
        float p_[4]; ushort4 pk_;                                             \
        _Pragma("unroll")                                                     \
        for (int r = 0; r < 4; ++r)                                           \
            p_[r] = (mrow_ + r < cnt) ? __expf(aS0[r] * 40.0f - gm0) : 0.0f;  \
        pk_.x = f2bf(p_[0]); pk_.y = f2bf(p_[1]);                             \
        pk_.z = f2bf(p_[2]); pk_.w = f2bf(p_[3]);                             \
        *(ushort4*)&P_s[PB][col][w * 16 + quad * 4] = pk_;                    \
        _Pragma("unroll")                                                     \
        for (int r = 0; r < 4; ++r)                                           \
            p_[r] = (mrow_ + r < cnt) ? __expf(aS1[r] * 40.0f - gm1) : 0.0f;  \
        pk_.x = f2bf(p_[0]); pk_.y = f2bf(p_[1]);                             \
        pk_.z = f2bf(p_[2]); pk_.w = f2bf(p_[3]);                             \
        *(ushort4*)&P_s[PB][16 + col][w * 16 + quad * 4] = pk_;               \
    }                                                                         \
    asm volatile("s_waitcnt lgkmcnt(0)" ::: "memory");                        \
    __builtin_amdgcn_s_barrier();                                             \
    __builtin_amdgcn_sched_barrier(0);                                        \
    _Pragma("unroll")                                                         \
    for (int k2 = 0; k2 < 2; ++k2) {                                          \
        short8 pb0_ = *(const short8*)&P_s[PB][col][k2 * 32 + quad * 8];      \
        short8 pb1_ = *(const short8*)&P_s[PB][16 + col][k2 * 32 + quad * 8]; \
        _Pragma("unroll")                                                     \
        for (int vt = 0; vt < 4; ++vt) {                                      \
            accO[vt][0] = MF(vf_[vt][k2], pb0_, accO[vt][0]);                 \
            accO[vt][1] = MF(vf_[vt][k2], pb1_, accO[vt][1]);                 \
        }                                                                     \
        if (doL) {                                                            \
            accL0 = MF(vones, pb0_, accL0);                                   \
            accL1 = MF(vones, pb1_, accL1);                                   \
        }                                                                     \
    }                                                                         \
} while (0)

    short8 kAh[4], kAl[4], kBh[4], kBl[4];
    int it = 0;
    if (it < it1) {
        LOADK(kAh, kAl, it);
        int itn;
        while (true) {
            itn = (it + 1 < it1) ? it + 1 : it;
            PV_PHASE(kAh, kAl, kBh, kBl, 0, it, itn);
            if (++it >= it1) break;
            itn = (it + 1 < it1) ? it + 1 : it;
            PV_PHASE(kBh, kBl, kAh, kAl, 1, it, itn);
            if (++it >= it1) break;
        }
    }
#undef PV_PHASE

    // ---- in-block denominator broadcast, then normalized gated output ----
    if (doL && lane < 16) {
        l_s[col] = accL0[0];        // q = col      (all acc rows identical)
        l_s[16 + col] = accL1[0];   // q = 16 + col
    }
    __syncthreads();
    const int qflag = qflags[b];
#pragma unroll
    for (int qt = 0; qt < 2; ++qt) {
        const int q = qb + qt * 16 + col;
        const float L = l_s[qt * 16 + col];
        const bool valid = (qflag != 0) && (cnt > 0) &&
                           (qmask[b * NQ + q] != 0) && (L > 0.f);
        const float rinv = valid ? 1.0f / L : 0.0f;
#pragma unroll
        for (int vt = 0; vt < 4; ++vt)
#pragma unroll
            for (int r = 0; r < 4; ++r) {
                int dv = dvh * 256 + w * 64 + vt * 16 + quad * 4 + r;
                out[((size_t)b * DV + dv) * NQ + q] = accO[vt][qt][r] * rinv;
            }
    }
}

// ---------------------------------------------------------------------------
extern "C" void kernel_launch(void* const* d_in, const int* in_sizes, int n_in,
                              void* d_out, int out_size, void* d_ws, size_t ws_size,
                              hipStream_t stream) {
    const float* qkey  = (const float*)d_in[0];
    // d_in[1] (qval) unused by the reference
    const int*   qmask = (const int*)d_in[2];
    const float* mkey  = (const float*)d_in[3];
    const float* mval  = (const float*)d_in[4];
    const int*   mmask = (const int*)d_in[5];
    float* out = (float*)d_out;

    char* ws = (char*)d_ws;
    size_t off = 0;
    const size_t QS  = (size_t)BATCH * NQ * DK * 2;          // 2 MB each
    const size_t KS2 = (size_t)BATCH * NM * DK * 2;          // 4 MB each (swizzled)
    const size_t VS  = (size_t)BATCH * NT * 2 * VTILE * 2;   // 16 MB
    ushort_t* Qhi = (ushort_t*)(ws + off); off += QS;
    ushort_t* Qlo = (ushort_t*)(ws + off); off += QS;
    ushort_t* Khi = (ushort_t*)(ws + off); off += KS2;
    ushort_t* Klo = (ushort_t*)(ws + off); off += KS2;
    ushort_t* Vc  = (ushort_t*)(ws + off); off += VS;
    float* mpart  = (float*)(ws + off); off += (size_t)BATCH * 4 * NQ * 4;
    int* cidx     = (int*)(ws + off); off += (size_t)BATCH * NM * 4;
    int* cpos     = (int*)(ws + off); off += (size_t)BATCH * NM * 4;
    int* cnts     = (int*)(ws + off); off += 64;
    int* qflags   = (int*)(ws + off); off += 64;

    scan_kernel<<<BATCH, 1024, 0, stream>>>(qmask, mmask, cidx, cpos, cnts, qflags);

    dim3 gq(NQ / 32, DK / 32, BATCH);
    prep_q_kernel<<<gq, 256, 0, stream>>>(qkey, Qhi, Qlo);
    dim3 gk(NM / 32, DK / 32, BATCH);
    prep_k_kernel<<<gk, 256, 0, stream>>>(mkey, mmask, cpos, Khi, Klo);

    dim3 gv(DV / 8, 9, BATCH);
    prep_v_kernel<<<gv, 256, 0, stream>>>(mval, mmask, cpos, cnts, Vc);

    stats_kernel<<<(NQ / 32) * 8, 256, 0, stream>>>(Qhi, Khi, cnts, mpart);

    pv_kernel<<<(NQ / 32) * 4, 256, 0, stream>>>(
        Qhi, Qlo, Khi, Klo, Vc, cnts, qflags, qmask, mpart, out);
}